// Round 5
// baseline (555.760 us; speedup 1.0000x reference)
//
#include <hip/hip_runtime.h>
#include <cstddef>

// Bit-exact OpenBLAS-skylakex (KC=320) fp32 SNN — r11: K1 8x8 tile.
// Chain order (verified r3/r4/r5): per (row,j) k ascending, panel folds at
// k=320/640 realized as 3 INDEPENDENT panel GEMMs (P1,P2,P3) combined as
// ((P1+P2)+P3)+b1 — identical association, bit-exact by construction.
// LIF literal order; layer2 cur2=mm+b2 then m2*0.25+cur2, j ascending.
//
// r11 (from r10 post-mortem):
//  - r10 K1+K2 ~= 250 us (both dropped out of rocprof top-5; fill=213 is
//    harness re-poison, + ~62 us launch overhead are a fixed ~275 floor).
//  - K1 is LDS-THROUGHPUT-bound: 4x8 tile = (4+8)/(4*8) = 0.375 floats/FMA
//    -> 4.93 GB LDS reads @ 52 TB/s (ds_read_b128 85 B/cy/CU) = 94 us.
//    8x8 tile = 0.25 floats/FMA -> 63 us bound. acc=64 VGPR: use 128-thr
//    blocks + __launch_bounds__(128,1) (cap 256: allocator CANNOT be forced
//    to spill — the r8/r9 trap; empirical cap law = 256/waves_arg).
//  - K1 grid 3*512=1536 x 128thr; LDS 33.8KB -> 4 blocks/CU resident,
//    6 blocks/CU total -> backfill absorbs panel-3's short tail (9 vs 20
//    k-tiles).
//  - ws 12-stride chunk layout + read pattern r6-verbatim (16 tx groups,
//    2-way-bank aliasing = free). x reads: 2x b128, 4 addrs/wave, clean.
//  - K2 (snn_dyn) r10-VERBATIM to isolate the K1 change.

typedef float f32x4 __attribute__((ext_vector_type(4)));

constexpr int KDIM   = 784;
constexpr int NJ     = 128;
constexpr int NO     = 10;
constexpr int TSTEPS = 20;

// ---------------- K1: panel GEMM (rows 64, 128 thr, 8x8 tile, BK=16) ------
constexpr int BR1 = 64;
constexpr int BK1 = 16;    // 320 = 20*16, 144 = 9*16

__global__ __launch_bounds__(128, 1) void snn_gemm(
    const float* __restrict__ x,
    const float* __restrict__ W1,
    float* __restrict__ out,
    int B)
{
    __shared__ alignas(16) float xs[2][BK1][72];    // [buf][kk][row(64)+pad]
    __shared__ alignas(16) float ws[2][BK1][192];   // [buf][kk][16 chunks*12]

    const int bid  = blockIdx.x;
    const int p    = bid % 3;                       // panel (mixed across CUs)
    const int rb   = bid / 3;
    const int kbeg = p * 320;
    const int nt   = (p < 2) ? 20 : 9;              // 320/16, 144/16
    const int t    = threadIdx.x;                   // 0..127
    const int tx   = t & 15;                        // j = tx*8+jj
    const int ty   = t >> 4;                        // row = ty*8+rr (0..7)
    const int r0   = rb * BR1;

    float acc[8][8];
    #pragma unroll
    for (int rr = 0; rr < 8; ++rr)
        #pragma unroll
        for (int jj = 0; jj < 8; ++jj) acc[rr][jj] = 0.0f;

    // staging maps (128 threads):
    //  x: 64 rows x 16 k = 1024 f / 128 thr = 8 f: row=t>>1, k-half=(t&1)*8
    //  W: 128 j x 16 k = 2048 f / 128 thr = 16 f: j=t, all 16 k
    const int xrow = t >> 1, xkf = (t & 1) * 8;
    const int wjr  = t;
    const int wco  = wjr >> 3, wci = wjr & 7;       // chunk / intra (r6 layout)
    const float* xrp = x  + (size_t)(r0 + xrow) * KDIM + kbeg + xkf;
    const float* wrp = W1 + (size_t)wjr * KDIM + kbeg;

    // preload tile 0 -> regs -> buf 0
    float4 xva = *(const float4*)(xrp);
    float4 xvb = *(const float4*)(xrp + 4);
    float4 wa  = *(const float4*)(wrp);
    float4 wb  = *(const float4*)(wrp + 4);
    float4 wc  = *(const float4*)(wrp + 8);
    float4 wd  = *(const float4*)(wrp + 12);
    {
        xs[0][xkf + 0][xrow] = xva.x; xs[0][xkf + 1][xrow] = xva.y;
        xs[0][xkf + 2][xrow] = xva.z; xs[0][xkf + 3][xrow] = xva.w;
        xs[0][xkf + 4][xrow] = xvb.x; xs[0][xkf + 5][xrow] = xvb.y;
        xs[0][xkf + 6][xrow] = xvb.z; xs[0][xkf + 7][xrow] = xvb.w;
        float* wp0 = &ws[0][0][wco * 12 + wci];     // k rows stride 192
        wp0[0*192]  = wa.x; wp0[1*192]  = wa.y; wp0[2*192]  = wa.z; wp0[3*192]  = wa.w;
        wp0[4*192]  = wb.x; wp0[5*192]  = wb.y; wp0[6*192]  = wb.z; wp0[7*192]  = wb.w;
        wp0[8*192]  = wc.x; wp0[9*192]  = wc.y; wp0[10*192] = wc.z; wp0[11*192] = wc.w;
        wp0[12*192] = wd.x; wp0[13*192] = wd.y; wp0[14*192] = wd.z; wp0[15*192] = wd.w;
    }
    __syncthreads();

    #pragma unroll 1
    for (int tt = 0; tt < nt; ++tt) {
        const int cb = tt & 1;
        if (tt < nt - 1) {                          // prefetch next tile -> regs
            const int k0n = (tt + 1) * BK1;
            xva = *(const float4*)(xrp + k0n);
            xvb = *(const float4*)(xrp + k0n + 4);
            wa  = *(const float4*)(wrp + k0n);
            wb  = *(const float4*)(wrp + k0n + 4);
            wc  = *(const float4*)(wrp + k0n + 8);
            wd  = *(const float4*)(wrp + k0n + 12);
        }
        #pragma unroll
        for (int kk = 0; kk < BK1; ++kk) {          // strict ascending k
            float4 xra = *(const float4*)&xs[cb][kk][ty * 8];
            float4 xrb = *(const float4*)&xs[cb][kk][ty * 8 + 4];
            float4 wva = *(const float4*)&ws[cb][kk][tx * 12];
            float4 wvb = *(const float4*)&ws[cb][kk][tx * 12 + 4];
            float xf[8] = {xra.x, xra.y, xra.z, xra.w, xrb.x, xrb.y, xrb.z, xrb.w};
            float wf[8] = {wva.x, wva.y, wva.z, wva.w, wvb.x, wvb.y, wvb.z, wvb.w};
            #pragma unroll
            for (int rr = 0; rr < 8; ++rr)
                #pragma unroll
                for (int jj = 0; jj < 8; ++jj)
                    acc[rr][jj] = fmaf(xf[rr], wf[jj], acc[rr][jj]);
        }
        if (tt < nt - 1) {                          // store prefetched tile
            const int nb = cb ^ 1;
            xs[nb][xkf + 0][xrow] = xva.x; xs[nb][xkf + 1][xrow] = xva.y;
            xs[nb][xkf + 2][xrow] = xva.z; xs[nb][xkf + 3][xrow] = xva.w;
            xs[nb][xkf + 4][xrow] = xvb.x; xs[nb][xkf + 5][xrow] = xvb.y;
            xs[nb][xkf + 6][xrow] = xvb.z; xs[nb][xkf + 7][xrow] = xvb.w;
            float* wp0 = &ws[nb][0][wco * 12 + wci];
            wp0[0*192]  = wa.x; wp0[1*192]  = wa.y; wp0[2*192]  = wa.z; wp0[3*192]  = wa.w;
            wp0[4*192]  = wb.x; wp0[5*192]  = wb.y; wp0[6*192]  = wb.z; wp0[7*192]  = wb.w;
            wp0[8*192]  = wc.x; wp0[9*192]  = wc.y; wp0[10*192] = wc.z; wp0[11*192] = wc.w;
            wp0[12*192] = wd.x; wp0[13*192] = wd.y; wp0[14*192] = wd.z; wp0[15*192] = wd.w;
        }
        __syncthreads();                            // ONE barrier per tile
    }

    // store panel partial into rec[17+p] scratch region
    // per rr: 16 tx x 32B = contiguous 512B per row -> NT merges cleanly
    float* part = out + (size_t)B * NO + ((size_t)(17 + p) * B) * NJ;
    #pragma unroll
    for (int rr = 0; rr < 8; ++rr) {
        float* pp = part + (size_t)(r0 + ty * 8 + rr) * NJ + tx * 8;
        f32x4 a = {acc[rr][0], acc[rr][1], acc[rr][2], acc[rr][3]};
        f32x4 b = {acc[rr][4], acc[rr][5], acc[rr][6], acc[rr][7]};
        __builtin_nontemporal_store(a, (f32x4*)pp);
        __builtin_nontemporal_store(b, (f32x4*)(pp + 4));
    }
}

// ---------------- K2: combine + LIF + layer2 (r10 VERBATIM) ---------------
constexpr int BR2 = 32;

__global__ __launch_bounds__(256, 2) void snn_dyn(
    const float* __restrict__ b1,
    const float* __restrict__ W2,
    const float* __restrict__ b2,
    float* __restrict__ out,
    int B)
{
    __shared__ alignas(16) float4 w2s[NJ][3];       // [j][og]: W2[og*4+c][j]*2^-(j&31)
    __shared__ unsigned smaskW[2][BR2][5];          // parity row masks (4 words + pad)
    __shared__ float b2s[12];

    const int t  = threadIdx.x;
    const int tx = t & 15;                          // j = tx*8+jj
    const int ty = t >> 4;                          // row = ty*2+rr
    const int r0 = blockIdx.x * BR2;

    // ---- one-time staging: W2 (o-transposed, scaled), b2 ----
    for (int e = t; e < NJ * 3; e += 256) {
        int og = e % 3, j = e / 3;
        float sc = __int_as_float((127 - (j & 31)) << 23);   // 2^-(j&31), exact
        float vv[4];
        #pragma unroll
        for (int c = 0; c < 4; ++c) {
            int o = og * 4 + c;
            vv[c] = (o < NO) ? W2[o * NJ + j] * sc : 0.0f;
        }
        float4 v; v.x = vv[0]; v.y = vv[1]; v.z = vv[2]; v.w = vv[3];
        w2s[j][og] = v;
    }
    if (t < 12) b2s[t] = (t < NO) ? b2[t] : 0.0f;

    // ---- combine partials: cur = ((P1+P2)+P3)+b1 (reads rec[17..19]) ----
    const float* part = out + (size_t)B * NO + ((size_t)17 * B) * NJ;
    float cur[2][8];
    {
        const float* b1p = b1 + tx * 8;
        float4 ba = *(const float4*)b1p, bb = *(const float4*)(b1p + 4);
        float bf[8] = {ba.x, ba.y, ba.z, ba.w, bb.x, bb.y, bb.z, bb.w};
        #pragma unroll
        for (int rr = 0; rr < 2; ++rr) {
            const float* pp = part + (size_t)(r0 + ty * 2 + rr) * NJ + tx * 8;
            const size_t ps = (size_t)B * NJ;       // panel stride
            float4 a0 = *(const float4*)(pp);          float4 a1 = *(const float4*)(pp + 4);
            float4 c0 = *(const float4*)(pp + ps);     float4 c1 = *(const float4*)(pp + ps + 4);
            float4 d0 = *(const float4*)(pp + 2 * ps); float4 d1 = *(const float4*)(pp + 2 * ps + 4);
            float p1[8] = {a0.x, a0.y, a0.z, a0.w, a1.x, a1.y, a1.z, a1.w};
            float p2[8] = {c0.x, c0.y, c0.z, c0.w, c1.x, c1.y, c1.z, c1.w};
            float p3[8] = {d0.x, d0.y, d0.z, d0.w, d1.x, d1.y, d1.z, d1.w};
            #pragma unroll
            for (int jj = 0; jj < 8; ++jj)
                cur[rr][jj] = ((p1[jj] + p2[jj]) + p3[jj]) + bf[jj];
        }
    }
    __syncthreads();                                // w2s/b2s ready

    // ---- LIF dynamics ----
    float mem1[2][8];
    #pragma unroll
    for (int rr = 0; rr < 2; ++rr)
        #pragma unroll
        for (int jj = 0; jj < 8; ++jj) mem1[rr][jj] = 0.0f;

    const int row_l2 = t & 31;                      // layer-2: row
    const int og     = t >> 5;                      // o-group; og<3 active
    float m2[4]  = {0.f, 0.f, 0.f, 0.f};
    float cnt[4] = {0.f, 0.f, 0.f, 0.f};
    float* rec = out + (size_t)B * NO;

    #pragma unroll 1
    for (int st = 0; st < TSTEPS; ++st) {
        const int pb = st & 1;
        #pragma unroll
        for (int rr = 0; rr < 2; ++rr) {
            unsigned bt = 0;
            #pragma unroll
            for (int jj = 0; jj < 8; ++jj) {
                float m = fmaf(mem1[rr][jj], 0.25f, cur[rr][jj]);  // *0.25 exact
                float v = m - 1.0f;
                bool  s = v > 0.0f;
                mem1[rr][jj] = s ? 0.0f : m;
                bt |= s ? (1u << jj) : 0u;
            }
            ((unsigned char*)&smaskW[pb][ty * 2 + rr][0])[tx] = (unsigned char)bt;
        }
        __syncthreads();

        // dense spike store pass: wave-instruction writes contiguous 1 KB.
        // Values rebuilt from bits are exactly 1.0f/0.0f == LIF's spike.
        {
            const size_t slab = ((size_t)st * B + (size_t)r0) * NJ;
            #pragma unroll
            for (int i = 0; i < 4; ++i) {
                int c   = i * 256 + t;              // chunk of 4 floats
                int row = c >> 5;
                int wi  = (c & 31) >> 3;
                int sh  = (c & 7) * 4;
                unsigned bits = smaskW[pb][row][wi] >> sh;
                f32x4 v = { (bits & 1u) ? 1.0f : 0.0f,
                            (bits & 2u) ? 1.0f : 0.0f,
                            (bits & 4u) ? 1.0f : 0.0f,
                            (bits & 8u) ? 1.0f : 0.0f };
                __builtin_nontemporal_store(v, (f32x4*)&rec[slab + (size_t)c * 4]);
            }
        }

        if (og < 3) {
            unsigned mw[4];
            #pragma unroll
            for (int w = 0; w < 4; ++w) mw[w] = smaskW[pb][row_l2][w];
            float mm[4] = {0.f, 0.f, 0.f, 0.f};
            #pragma unroll
            for (int w = 0; w < 4; ++w) {
                unsigned bits = mw[w];
                #pragma unroll
                for (int b = 0; b < 32; ++b) {      // strict ascending j
                    float f = (float)(bits & (1u << b));      // 0 or 2^b, exact
                    float4 wv = w2s[w * 32 + b][og];          // W2 * 2^-b
                    mm[0] = fmaf(f, wv.x, mm[0]);
                    mm[1] = fmaf(f, wv.y, mm[1]);
                    mm[2] = fmaf(f, wv.z, mm[2]);
                    mm[3] = fmaf(f, wv.w, mm[3]);
                }
            }
            #pragma unroll
            for (int c = 0; c < 4; ++c) {
                float cur2 = mm[c] + b2s[og * 4 + c];   // np: chain + b2
                float nm   = fmaf(m2[c], 0.25f, cur2);  // then decay add (exact mul)
                float v2   = nm - 1.0f;
                bool  s2   = v2 > 0.0f;
                cnt[c] += s2 ? 1.0f : 0.0f;
                m2[c]  = s2 ? 0.0f : nm;
            }
        }
    }

    if (og < 3) {
        #pragma unroll
        for (int c = 0; c < 4; ++c) {
            int o = og * 4 + c;
            if (o < NO) out[(size_t)(r0 + row_l2) * NO + o] = cnt[c];
        }
    }
}

extern "C" void kernel_launch(void* const* d_in, const int* in_sizes, int n_in,
                              void* d_out, int out_size, void* d_ws, size_t ws_size,
                              hipStream_t stream)
{
    const float* x  = (const float*)d_in[0];
    const float* W1 = (const float*)d_in[1];
    const float* b1 = (const float*)d_in[2];
    const float* W2 = (const float*)d_in[3];
    const float* b2 = (const float*)d_in[4];
    float* out = (float*)d_out;
    const int B = in_sizes[0] / KDIM;       // 32768
    snn_gemm<<<3 * (B / BR1), 128, 0, stream>>>(x, W1, out, B);
    snn_dyn<<<B / BR2, 256, 0, stream>>>(b1, W2, b2, out, B);
}

// Round 6
// 541.646 us; speedup vs baseline: 1.0261x; 1.0261x over previous
//
#include <hip/hip_runtime.h>
#include <cstddef>

// Bit-exact OpenBLAS-skylakex (KC=320) fp32 SNN — r12: fused, BROWS=32,
// dense mask-rebuilt spike stores.
// Chain order (verified r3/r4/r5): per (row,j) k ascending, panel folds at
// k=320/640, ((P1+P2)+P3)+b1; LIF literal order; layer2 cur2=mm+b2 then
// m2*0.25+cur2, j ascending.
//
// r12 (from r11 post-mortem — recombination of PROVEN pieces):
//  - Fused beats split: r6 fused kernel 227us vs r10 split K1+K2 ~250us
//    (partial round-trip ~100MB + 2nd launch). Stay fused.
//  - Phase 1 is VALU/latency-bound, NOT LDS-bound (LDS broadcasts dedup
//    same-address lane reads; ~576B/wave/kk vs 128 VALU cyc/kk/CU). So the
//    lever is occupancy for barrier-latency hiding: BROWS=32 -> grid 1024
//    = 4 blocks/CU = 16 waves/CU. Phase-1 body is r7's (passed bit-exact).
//  - r7's two defects fixed: (a) __launch_bounds__(256,2) (cap law 256/w:
//    (256,4) capped VGPR at 64 and strangled codegen), (b) r7's scattered
//    NT spike stores amplified WRITE 373->900MB; use r8-K2's PROVEN dense
//    pass: masks->LDS, barrier, each wave rebuilds+stores contiguous 1KB.
//  - Layer-2 = r8-K2 verbatim (og=t>>5, 96 active lanes, bit-trick FMA).
// LDS ~36.7KB (4 blocks/CU), VGPR ~100 (4 waves/SIMD).

typedef float f32x4 __attribute__((ext_vector_type(4)));

constexpr int BROWS  = 32;
constexpr int BK     = 16;    // 784 = 49*16; KC=320 folds after tiles 19,39
constexpr int NJ     = 128;
constexpr int KDIM   = 784;
constexpr int NO     = 10;
constexpr int TSTEPS = 20;

__global__ __launch_bounds__(256, 2) void snn_fused(
    const float* __restrict__ x,
    const float* __restrict__ W1,
    const float* __restrict__ b1,
    const float* __restrict__ W2,
    const float* __restrict__ b2,
    float* __restrict__ out,
    int B)
{
    __shared__ alignas(16) float xs[2][BK][36];    // [buf][kk][row(32)+pad]
    __shared__ alignas(16) float ws[2][BK][192];   // [buf][kk][16 chunks*12]
    __shared__ alignas(16) float4 w2s[NJ][3];      // [j][og]: W2[og*4+c][j]*2^-(j&31)
    __shared__ unsigned smaskW[2][BROWS][5];       // parity row masks (4 words+pad)
    __shared__ float b2s[12];

    const int t  = threadIdx.x;
    const int tx = t & 15;                         // col group: j = tx*8+jj
    const int ty = t >> 4;                         // row group: r = ty*2+rr
    const int r0 = blockIdx.x * BROWS;

    // ---- one-time staging: W2 (o-transposed, scaled), b2 ----
    for (int e = t; e < NJ * 3; e += 256) {
        int og = e % 3, j = e / 3;
        float sc = __int_as_float((127 - (j & 31)) << 23);   // 2^-(j&31), exact
        float vv[4];
        #pragma unroll
        for (int c = 0; c < 4; ++c) {
            int o = og * 4 + c;
            vv[c] = (o < NO) ? W2[o * NJ + j] * sc : 0.0f;
        }
        float4 v; v.x = vv[0]; v.y = vv[1]; v.z = vv[2]; v.w = vv[3];
        w2s[j][og] = v;
    }
    if (t < 12) b2s[t] = (t < NO) ? b2[t] : 0.0f;

    // ---- phase 1: fp32 GEMM (r7 body), panel folds at k=320,640 ----
    float acc[2][8], cur[2][8];
    #pragma unroll
    for (int rr = 0; rr < 2; ++rr)
        #pragma unroll
        for (int jj = 0; jj < 8; ++jj) { acc[rr][jj] = 0.0f; cur[rr][jj] = 0.0f; }

    const int xrow = t >> 3, xkf = (t & 7) * 2;    // x stage: row(0..31), 2-k chunk
    const int wjr  = t >> 1, wkf = (t & 1) * 8;    // W1 stage: j, 8-k chunk
    const int wco  = wjr >> 3, wci = wjr & 7;      // chunk / intra
    const float* xrp = x  + (size_t)(r0 + xrow) * KDIM + xkf;
    const float* wrp = W1 + (size_t)wjr * KDIM + wkf;

    // preload tile 0 -> regs -> buf 0
    float2 xv = *(const float2*)(xrp);
    float4 wa = *(const float4*)(wrp);
    float4 wb = *(const float4*)(wrp + 4);
    {
        xs[0][xkf][xrow] = xv.x; xs[0][xkf + 1][xrow] = xv.y;
        float* wp0 = &ws[0][wkf][wco * 12 + wci];  // rows wkf..wkf+7, stride 192
        wp0[0]    = wa.x; wp0[192]  = wa.y; wp0[384]  = wa.z; wp0[576]  = wa.w;
        wp0[768]  = wb.x; wp0[960]  = wb.y; wp0[1152] = wb.z; wp0[1344] = wb.w;
    }
    __syncthreads();

    #pragma unroll 1
    for (int tt = 0; tt < 49; ++tt) {
        const int cb = tt & 1;
        if (tt < 48) {                             // prefetch next tile -> regs
            const int k0n = (tt + 1) * BK;
            xv = *(const float2*)(xrp + k0n);
            wa = *(const float4*)(wrp + k0n);
            wb = *(const float4*)(wrp + k0n + 4);
        }
        #pragma unroll
        for (int kk = 0; kk < BK; ++kk) {          // strict ascending k
            float2 xr  = *(const float2*)&xs[cb][kk][ty * 2];
            float4 wva = *(const float4*)&ws[cb][kk][tx * 12];
            float4 wvb = *(const float4*)&ws[cb][kk][tx * 12 + 4];
            float xf[2] = {xr.x, xr.y};
            float wf[8] = {wva.x, wva.y, wva.z, wva.w, wvb.x, wvb.y, wvb.z, wvb.w};
            #pragma unroll
            for (int rr = 0; rr < 2; ++rr)
                #pragma unroll
                for (int jj = 0; jj < 8; ++jj)
                    acc[rr][jj] = fmaf(xf[rr], wf[jj], acc[rr][jj]);
        }
        if (tt == 19) {                            // end panel 1 [0,320)
            #pragma unroll
            for (int rr = 0; rr < 2; ++rr)
                #pragma unroll
                for (int jj = 0; jj < 8; ++jj) { cur[rr][jj] = acc[rr][jj]; acc[rr][jj] = 0.0f; }
        } else if (tt == 39) {                     // end panel 2 [320,640)
            #pragma unroll
            for (int rr = 0; rr < 2; ++rr)
                #pragma unroll
                for (int jj = 0; jj < 8; ++jj) { cur[rr][jj] = cur[rr][jj] + acc[rr][jj]; acc[rr][jj] = 0.0f; }
        }
        if (tt < 48) {                             // store prefetched tile
            const int nb = cb ^ 1;
            xs[nb][xkf][xrow] = xv.x; xs[nb][xkf + 1][xrow] = xv.y;
            float* wp0 = &ws[nb][wkf][wco * 12 + wci];
            wp0[0]    = wa.x; wp0[192]  = wa.y; wp0[384]  = wa.z; wp0[576]  = wa.w;
            wp0[768]  = wb.x; wp0[960]  = wb.y; wp0[1152] = wb.z; wp0[1344] = wb.w;
        }
        __syncthreads();                           // ONE barrier per tile
    }
    {
        const float* b1p = b1 + tx * 8;
        float4 ba = *(const float4*)b1p, bb = *(const float4*)(b1p + 4);
        float bf[8] = {ba.x, ba.y, ba.z, ba.w, bb.x, bb.y, bb.z, bb.w};
        #pragma unroll
        for (int rr = 0; rr < 2; ++rr)
            #pragma unroll
            for (int jj = 0; jj < 8; ++jj)
                cur[rr][jj] = (cur[rr][jj] + acc[rr][jj]) + bf[jj];   // +P3, +b1
    }

    // ---- phase 2: LIF + dense spike stores + layer2 (r8-K2 body) ----
    float mem1[2][8];
    #pragma unroll
    for (int rr = 0; rr < 2; ++rr)
        #pragma unroll
        for (int jj = 0; jj < 8; ++jj) mem1[rr][jj] = 0.0f;

    const int row_l2 = t & 31;                     // layer-2: row
    const int og     = t >> 5;                     // o-group; og<3 active
    float m2[4]  = {0.f, 0.f, 0.f, 0.f};
    float cnt[4] = {0.f, 0.f, 0.f, 0.f};
    float* rec = out + (size_t)B * NO;

    #pragma unroll 1
    for (int st = 0; st < TSTEPS; ++st) {
        const int pb = st & 1;
        #pragma unroll
        for (int rr = 0; rr < 2; ++rr) {
            unsigned bt = 0;
            #pragma unroll
            for (int jj = 0; jj < 8; ++jj) {
                float m = fmaf(mem1[rr][jj], 0.25f, cur[rr][jj]);  // *0.25 exact
                float v = m - 1.0f;
                bool  s = v > 0.0f;
                mem1[rr][jj] = s ? 0.0f : m;
                bt |= s ? (1u << jj) : 0u;
            }
            ((unsigned char*)&smaskW[pb][ty * 2 + rr][0])[tx] = (unsigned char)bt;
        }
        __syncthreads();

        // dense spike store pass: each wave-instruction writes contiguous 1 KB.
        // Values rebuilt from bits are exactly 1.0f/0.0f == LIF's spike.
        {
            const size_t slab = ((size_t)st * B + (size_t)r0) * NJ;
            #pragma unroll
            for (int i = 0; i < 4; ++i) {
                int c   = i * 256 + t;              // chunk of 4 floats
                int row = c >> 5;
                int wi  = (c & 31) >> 3;
                int sh  = (c & 7) * 4;
                unsigned bits = smaskW[pb][row][wi] >> sh;
                f32x4 v = { (bits & 1u) ? 1.0f : 0.0f,
                            (bits & 2u) ? 1.0f : 0.0f,
                            (bits & 4u) ? 1.0f : 0.0f,
                            (bits & 8u) ? 1.0f : 0.0f };
                __builtin_nontemporal_store(v, (f32x4*)&rec[slab + (size_t)c * 4]);
            }
        }

        if (og < 3) {
            unsigned mw[4];
            #pragma unroll
            for (int w = 0; w < 4; ++w) mw[w] = smaskW[pb][row_l2][w];
            float mm[4] = {0.f, 0.f, 0.f, 0.f};
            #pragma unroll
            for (int w = 0; w < 4; ++w) {
                unsigned bits = mw[w];
                #pragma unroll
                for (int b = 0; b < 32; ++b) {      // strict ascending j
                    float f = (float)(bits & (1u << b));      // 0 or 2^b, exact
                    float4 wv = w2s[w * 32 + b][og];          // W2 * 2^-b
                    mm[0] = fmaf(f, wv.x, mm[0]);
                    mm[1] = fmaf(f, wv.y, mm[1]);
                    mm[2] = fmaf(f, wv.z, mm[2]);
                    mm[3] = fmaf(f, wv.w, mm[3]);
                }
            }
            #pragma unroll
            for (int c = 0; c < 4; ++c) {
                float cur2 = mm[c] + b2s[og * 4 + c];   // np: chain + b2
                float nm   = fmaf(m2[c], 0.25f, cur2);  // then decay add (exact mul)
                float v2   = nm - 1.0f;
                bool  s2   = v2 > 0.0f;
                cnt[c] += s2 ? 1.0f : 0.0f;
                m2[c]  = s2 ? 0.0f : nm;
            }
        }
    }

    if (og < 3) {
        #pragma unroll
        for (int c = 0; c < 4; ++c) {
            int o = og * 4 + c;
            if (o < NO) out[(size_t)(r0 + row_l2) * NO + o] = cnt[c];
        }
    }
}

extern "C" void kernel_launch(void* const* d_in, const int* in_sizes, int n_in,
                              void* d_out, int out_size, void* d_ws, size_t ws_size,
                              hipStream_t stream)
{
    const float* x  = (const float*)d_in[0];
    const float* W1 = (const float*)d_in[1];
    const float* b1 = (const float*)d_in[2];
    const float* W2 = (const float*)d_in[3];
    const float* b2 = (const float*)d_in[4];
    float* out = (float*)d_out;
    const int B = in_sizes[0] / KDIM;       // 32768
    snn_fused<<<B / BROWS, 256, 0, stream>>>(x, W1, b1, W2, b2, out, B);
}

// Round 8
// 499.963 us; speedup vs baseline: 1.1116x; 1.0834x over previous
//
#include <hip/hip_runtime.h>
#include <cstddef>

// Bit-exact OpenBLAS-skylakex (KC=320) fp32 SNN.
// Chain order (PASSED r3/r4/r5): k ascending, panel folds at k=320/640,
// ((P1+P2)+P3)+b1; LIF literal order; layer2 cur2=mm+b2 then m2*0.25+cur2,
// j ascending.
// r14 = r13 RESUBMIT (round-7 bench died with "container failed twice" —
// infra, not kernel: the asm barrier is uniform [top-level in st loop, all
// 256 threads, no early exit], NT-store backpressure throttles rather than
// hangs, and the failure signature matches the session's prior acquire
// flakes).
// r13 = r6 champion VERBATIM (BROWS=64, 4x8 tile, double-buffered xs/ws,
// ONE barrier per tile, register prefetch, nontemporal rec stores) + ONE
// change, from the r12 post-mortem ledger:
//  - The phase-2 st-loop barrier was __syncthreads(), which emits
//    s_waitcnt vmcnt(0) before s_barrier (m97 evidence) -> every timestep
//    DRAINED the 64KB/CU of NT spike stores at HBM rate (~6.2k cy/st,
//    ~52us serialized over 20 steps; matches phase-2's 112us vs ~60us
//    compute+write-overlap floor).
//  - Replaced with a single asm block: s_waitcnt lgkmcnt(0) + s_barrier.
//    The barrier only needs LDS (mask) visibility; NT stores write
//    addresses never read by the kernel, so they float across iterations
//    and drain under layer-2/LIF compute. vmcnt naturally throttles at
//    its cap. Memory clobber keeps compiler ordering; both instructions
//    in ONE asm so nothing is scheduled between them.
// Ledger (don't redo): BROWS=32 loses (r7/r12: +25% phase-1 issue overhead);
// split-K loses (r10: ~250us vs 227 fused, partial round-trip);
// __launch_bounds__(256,w) caps VGPR at 256/w (r8/r9 spills at w>=4);
// 8x8/128thr tile loses (r11); dense rebuild stores = clean WRITE but not
// needed once the barrier stops draining (direct stores cost 0 extra instr).

typedef float f32x4 __attribute__((ext_vector_type(4)));

constexpr int BROWS  = 64;
constexpr int BK     = 16;    // 784 = 49*16; KC=320 folds after tiles 19,39
constexpr int NJ     = 128;
constexpr int KDIM   = 784;
constexpr int NO     = 10;
constexpr int TSTEPS = 20;

__global__ __launch_bounds__(256, 2) void snn_fused(
    const float* __restrict__ x,
    const float* __restrict__ W1,
    const float* __restrict__ b1,
    const float* __restrict__ W2,
    const float* __restrict__ b2,
    float* __restrict__ out,
    int B)
{
    __shared__ alignas(16) float xs[2][BK][68];    // [buf][kk][row(64)+pad]
    __shared__ alignas(16) float ws[2][BK][192];   // [buf][kk][16 chunks * 12]
    __shared__ alignas(16) float4 w2s[NJ][3];      // [j][og]: W2[og*4+c][j]*2^-(j&31)
    __shared__ unsigned smaskW[2][BROWS][17];      // parity row masks
    __shared__ float b2s[12];

    const int t  = threadIdx.x;
    const int tx = t & 15;                         // col group: j = tx*8+jj
    const int ty = t >> 4;                         // row group: r = ty*4+rr
    const int r0 = blockIdx.x * BROWS;

    // ---- one-time staging: W2 (o-transposed, scaled), b2 ----
    for (int e = t; e < NJ * 3; e += 256) {
        int og = e % 3, j = e / 3;
        float sc = __int_as_float((127 - (j & 31)) << 23);   // 2^-(j&31), exact
        float vv[4];
        #pragma unroll
        for (int c = 0; c < 4; ++c) {
            int o = og * 4 + c;
            vv[c] = (o < NO) ? W2[o * NJ + j] * sc : 0.0f;
        }
        float4 v; v.x = vv[0]; v.y = vv[1]; v.z = vv[2]; v.w = vv[3];
        w2s[j][og] = v;
    }
    if (t < 12) b2s[t] = (t < NO) ? b2[t] : 0.0f;

    // ---- phase 1: fp32 GEMM, panel folds at k=320,640 ----
    float acc[4][8], cur[4][8];
    #pragma unroll
    for (int rr = 0; rr < 4; ++rr)
        #pragma unroll
        for (int jj = 0; jj < 8; ++jj) { acc[rr][jj] = 0.0f; cur[rr][jj] = 0.0f; }

    const int xrow = t >> 2, xkf = (t & 3) * 4;    // x stage: row, 4-k chunk
    const int wj   = t >> 1, wkf = (t & 1) * 8;    // W1 stage: j, 8-k chunk
    const int wco  = wj >> 3, wci = wj & 7;        // chunk / intra
    const float* xrp = x  + (size_t)(r0 + xrow) * KDIM + xkf;
    const float* wrp = W1 + (size_t)wj * KDIM + wkf;

    // preload tile 0 -> regs -> buf 0
    float4 xv = *(const float4*)(xrp);
    float4 wa = *(const float4*)(wrp);
    float4 wb = *(const float4*)(wrp + 4);
    {
        xs[0][xkf + 0][xrow] = xv.x; xs[0][xkf + 1][xrow] = xv.y;
        xs[0][xkf + 2][xrow] = xv.z; xs[0][xkf + 3][xrow] = xv.w;
        float* wp0 = &ws[0][wkf][wco * 12 + wci];  // rows wkf..wkf+7, stride 192
        wp0[0]    = wa.x; wp0[192]  = wa.y; wp0[384]  = wa.z; wp0[576]  = wa.w;
        wp0[768]  = wb.x; wp0[960]  = wb.y; wp0[1152] = wb.z; wp0[1344] = wb.w;
    }
    __syncthreads();

    #pragma unroll 1
    for (int tt = 0; tt < 49; ++tt) {
        const int cb = tt & 1;
        if (tt < 48) {                             // prefetch next tile -> regs
            const int k0n = (tt + 1) * BK;
            xv = *(const float4*)(xrp + k0n);
            wa = *(const float4*)(wrp + k0n);
            wb = *(const float4*)(wrp + k0n + 4);
        }
        #pragma unroll
        for (int kk = 0; kk < BK; ++kk) {          // strict ascending k
            float4 xr  = *(const float4*)&xs[cb][kk][ty * 4];
            float4 wva = *(const float4*)&ws[cb][kk][tx * 12];
            float4 wvb = *(const float4*)&ws[cb][kk][tx * 12 + 4];
            float xf[4] = {xr.x, xr.y, xr.z, xr.w};
            float wf[8] = {wva.x, wva.y, wva.z, wva.w, wvb.x, wvb.y, wvb.z, wvb.w};
            #pragma unroll
            for (int rr = 0; rr < 4; ++rr)
                #pragma unroll
                for (int jj = 0; jj < 8; ++jj)
                    acc[rr][jj] = fmaf(xf[rr], wf[jj], acc[rr][jj]);
        }
        if (tt == 19) {                            // end panel 1 [0,320)
            #pragma unroll
            for (int rr = 0; rr < 4; ++rr)
                #pragma unroll
                for (int jj = 0; jj < 8; ++jj) { cur[rr][jj] = acc[rr][jj]; acc[rr][jj] = 0.0f; }
        } else if (tt == 39) {                     // end panel 2 [320,640)
            #pragma unroll
            for (int rr = 0; rr < 4; ++rr)
                #pragma unroll
                for (int jj = 0; jj < 8; ++jj) { cur[rr][jj] = cur[rr][jj] + acc[rr][jj]; acc[rr][jj] = 0.0f; }
        }
        if (tt < 48) {                             // store prefetched tile
            const int nb = cb ^ 1;
            xs[nb][xkf + 0][xrow] = xv.x; xs[nb][xkf + 1][xrow] = xv.y;
            xs[nb][xkf + 2][xrow] = xv.z; xs[nb][xkf + 3][xrow] = xv.w;
            float* wp0 = &ws[nb][wkf][wco * 12 + wci];
            wp0[0]    = wa.x; wp0[192]  = wa.y; wp0[384]  = wa.z; wp0[576]  = wa.w;
            wp0[768]  = wb.x; wp0[960]  = wb.y; wp0[1152] = wb.z; wp0[1344] = wb.w;
        }
        __syncthreads();                           // ONE barrier per tile
    }
    {
        const float* b1p = b1 + tx * 8;
        float4 ba = *(const float4*)b1p, bb = *(const float4*)(b1p + 4);
        float bf[8] = {ba.x, ba.y, ba.z, ba.w, bb.x, bb.y, bb.z, bb.w};
        #pragma unroll
        for (int rr = 0; rr < 4; ++rr)
            #pragma unroll
            for (int jj = 0; jj < 8; ++jj)
                cur[rr][jj] = (cur[rr][jj] + acc[rr][jj]) + bf[jj];   // +P3, +b1
    }

    // ---- phase 2: LIF dynamics (r6 verbatim, non-draining barrier) ----
    float mem1[4][8];
    #pragma unroll
    for (int rr = 0; rr < 4; ++rr)
        #pragma unroll
        for (int jj = 0; jj < 8; ++jj) mem1[rr][jj] = 0.0f;

    const int row_l2 = t & 63;                     // layer-2: row
    const int og     = t >> 6;                     // o-group (wave-uniform); 3=idle
    float m2[4]  = {0.f, 0.f, 0.f, 0.f};
    float cnt[4] = {0.f, 0.f, 0.f, 0.f};
    float* rec = out + (size_t)B * NO;

    #pragma unroll 1
    for (int st = 0; st < TSTEPS; ++st) {
        const int p = st & 1;
        #pragma unroll
        for (int rr = 0; rr < 4; ++rr) {
            unsigned bt = 0;
            float s0[8];
            #pragma unroll
            for (int jj = 0; jj < 8; ++jj) {
                float m = fmaf(mem1[rr][jj], 0.25f, cur[rr][jj]);  // *0.25 exact
                float v = m - 1.0f;
                bool  s = v > 0.0f;
                s0[jj] = s ? 1.0f : 0.0f;
                mem1[rr][jj] = s ? 0.0f : m;
                bt |= s ? (1u << jj) : 0u;
            }
            size_t base = ((size_t)st * B + (size_t)(r0 + ty * 4 + rr)) * NJ + tx * 8;
            f32x4 fa = {s0[0], s0[1], s0[2], s0[3]};
            f32x4 fb = {s0[4], s0[5], s0[6], s0[7]};
            __builtin_nontemporal_store(fa, (f32x4*)&rec[base]);
            __builtin_nontemporal_store(fb, (f32x4*)&rec[base + 4]);
            ((unsigned char*)&smaskW[p][ty * 4 + rr][0])[tx] = (unsigned char)bt;
        }
        // Non-draining barrier: wait LDS (mask writes) only, NOT vmcnt —
        // the NT spike stores are never read by this kernel and drain in
        // the background under layer-2/LIF compute. __syncthreads would
        // emit s_waitcnt vmcnt(0) and serialize ~64KB/CU of stores per st.
        asm volatile("s_waitcnt lgkmcnt(0)\n\ts_barrier" ::: "memory");
        if (og < 3) {
            unsigned mw[4];
            #pragma unroll
            for (int w = 0; w < 4; ++w) mw[w] = smaskW[p][row_l2][w];
            float mm[4] = {0.f, 0.f, 0.f, 0.f};
            #pragma unroll
            for (int w = 0; w < 4; ++w) {
                unsigned bits = mw[w];
                #pragma unroll
                for (int b = 0; b < 32; ++b) {     // strict ascending j
                    float f = (float)(bits & (1u << b));      // 0 or 2^b, exact
                    float4 wv = w2s[w * 32 + b][og];          // W2 * 2^-b
                    mm[0] = fmaf(f, wv.x, mm[0]);
                    mm[1] = fmaf(f, wv.y, mm[1]);
                    mm[2] = fmaf(f, wv.z, mm[2]);
                    mm[3] = fmaf(f, wv.w, mm[3]);
                }
            }
            #pragma unroll
            for (int c = 0; c < 4; ++c) {
                float cur2 = mm[c] + b2s[og * 4 + c];   // np: chain + b2
                float nm   = fmaf(m2[c], 0.25f, cur2);  // then decay add (exact mul)
                float v2   = nm - 1.0f;
                bool  s2   = v2 > 0.0f;
                cnt[c] += s2 ? 1.0f : 0.0f;
                m2[c]  = s2 ? 0.0f : nm;
            }
        }
    }

    if (og < 3) {
        #pragma unroll
        for (int c = 0; c < 4; ++c) {
            int o = og * 4 + c;
            if (o < NO) out[(size_t)(r0 + row_l2) * NO + o] = cnt[c];
        }
    }
}

extern "C" void kernel_launch(void* const* d_in, const int* in_sizes, int n_in,
                              void* d_out, int out_size, void* d_ws, size_t ws_size,
                              hipStream_t stream)
{
    const float* x  = (const float*)d_in[0];
    const float* W1 = (const float*)d_in[1];
    const float* b1 = (const float*)d_in[2];
    const float* W2 = (const float*)d_in[3];
    const float* b2 = (const float*)d_in[4];
    float* out = (float*)d_out;
    const int B = in_sizes[0] / KDIM;       // 32768
    snn_fused<<<B / BROWS, 256, 0, stream>>>(x, W1, b1, W2, b2, out, B);
}

// Round 10
// 481.260 us; speedup vs baseline: 1.1548x; 1.0389x over previous
//
#include <hip/hip_runtime.h>
#include <cstddef>

// Bit-exact OpenBLAS-skylakex (KC=320) fp32 SNN.
// Chain order (PASSED r3/r4/r5): k ascending, panel folds at k=320/640,
// ((P1+P2)+P3)+b1; LIF literal order; layer2 cur2=mm+b2 then m2*0.25+cur2,
// j ascending.
// r16 = r15 with the scratch-placement bug fixed:
//  - r15 FAILED (absmax 14): the scaled-W2 table lived at the head of the
//    rec[17] slab, but rec[17] is WRITTEN by every block's st=17 spike
//    stores while other blocks still read the table (all 512 blocks
//    co-resident) -> clobber race. r8's partials were safe only because
//    each block read its OWN rows; a global-shared table is not.
//  - Fix: table lives in d_ws (harness workspace, 6KB, touched by nothing
//    else). Kernel-boundary release/acquire makes prep's writes visible
//    across XCDs.
//  - Theory under test (from r13-null revision): layer-2's 128 wave-uniform
//    ds_read_b128 per st per wave occupy the CU LDS pipe (~51us over the
//    st loop, with dependent FMAs). W2 is wave-uniform -> scalar s_load
//    from K$-resident table (SMEM pipe overlaps VALU). w2s/b2s LDS gone.
// Ledger (don't redo): BROWS=32 loses (r7/r12); split-K loses (r10);
// launch_bounds cap = 256/w (r8/r9 spills); 8x8/128thr loses (r11);
// phase-2 barrier vmcnt drain is NOT a cost (r13 null); shared scratch in
// rec[17..19] races when globally read (r15).

typedef float f32x4 __attribute__((ext_vector_type(4)));

constexpr int BROWS  = 64;
constexpr int BK     = 16;    // 784 = 49*16; KC=320 folds after tiles 19,39
constexpr int NJ     = 128;
constexpr int KDIM   = 784;
constexpr int NO     = 10;
constexpr int TSTEPS = 20;

// ---- prep: scaled o-transposed W2 table -> d_ws (6KB) ----
__global__ void snn_prep(const float* __restrict__ W2,
                         float4* __restrict__ w2t)
{
    const int t = threadIdx.x;
    for (int e = t; e < 3 * NJ; e += 256) {
        int og = e >> 7, j = e & 127;                        // [og][j]
        float sc = __int_as_float((127 - (j & 31)) << 23);   // 2^-(j&31), exact
        float vv[4];
        #pragma unroll
        for (int c = 0; c < 4; ++c) {
            int o = og * 4 + c;
            vv[c] = (o < NO) ? W2[o * NJ + j] * sc : 0.0f;
        }
        float4 v; v.x = vv[0]; v.y = vv[1]; v.z = vv[2]; v.w = vv[3];
        w2t[e] = v;
    }
}

__global__ __launch_bounds__(256, 2) void snn_fused(
    const float* __restrict__ x,
    const float* __restrict__ W1,
    const float* __restrict__ b1,
    const float4* __restrict__ w2tab,   // d_ws table [og][j], scaled
    const float* __restrict__ b2,
    float* __restrict__ out,
    int B)
{
    __shared__ alignas(16) float xs[2][BK][68];    // [buf][kk][row(64)+pad]
    __shared__ alignas(16) float ws[2][BK][192];   // [buf][kk][16 chunks * 12]
    __shared__ unsigned smaskW[2][BROWS][17];      // parity row masks

    const int t  = threadIdx.x;
    const int tx = t & 15;                         // col group: j = tx*8+jj
    const int ty = t >> 4;                         // row group: r = ty*4+rr
    const int r0 = blockIdx.x * BROWS;

    // ---- phase 1: fp32 GEMM, panel folds at k=320,640 (r6 verbatim) ----
    float acc[4][8], cur[4][8];
    #pragma unroll
    for (int rr = 0; rr < 4; ++rr)
        #pragma unroll
        for (int jj = 0; jj < 8; ++jj) { acc[rr][jj] = 0.0f; cur[rr][jj] = 0.0f; }

    const int xrow = t >> 2, xkf = (t & 3) * 4;    // x stage: row, 4-k chunk
    const int wj   = t >> 1, wkf = (t & 1) * 8;    // W1 stage: j, 8-k chunk
    const int wco  = wj >> 3, wci = wj & 7;        // chunk / intra
    const float* xrp = x  + (size_t)(r0 + xrow) * KDIM + xkf;
    const float* wrp = W1 + (size_t)wj * KDIM + wkf;

    // preload tile 0 -> regs -> buf 0
    float4 xv = *(const float4*)(xrp);
    float4 wa = *(const float4*)(wrp);
    float4 wb = *(const float4*)(wrp + 4);
    {
        xs[0][xkf + 0][xrow] = xv.x; xs[0][xkf + 1][xrow] = xv.y;
        xs[0][xkf + 2][xrow] = xv.z; xs[0][xkf + 3][xrow] = xv.w;
        float* wp0 = &ws[0][wkf][wco * 12 + wci];  // rows wkf..wkf+7, stride 192
        wp0[0]    = wa.x; wp0[192]  = wa.y; wp0[384]  = wa.z; wp0[576]  = wa.w;
        wp0[768]  = wb.x; wp0[960]  = wb.y; wp0[1152] = wb.z; wp0[1344] = wb.w;
    }
    __syncthreads();

    #pragma unroll 1
    for (int tt = 0; tt < 49; ++tt) {
        const int cb = tt & 1;
        if (tt < 48) {                             // prefetch next tile -> regs
            const int k0n = (tt + 1) * BK;
            xv = *(const float4*)(xrp + k0n);
            wa = *(const float4*)(wrp + k0n);
            wb = *(const float4*)(wrp + k0n + 4);
        }
        #pragma unroll
        for (int kk = 0; kk < BK; ++kk) {          // strict ascending k
            float4 xr  = *(const float4*)&xs[cb][kk][ty * 4];
            float4 wva = *(const float4*)&ws[cb][kk][tx * 12];
            float4 wvb = *(const float4*)&ws[cb][kk][tx * 12 + 4];
            float xf[4] = {xr.x, xr.y, xr.z, xr.w};
            float wf[8] = {wva.x, wva.y, wva.z, wva.w, wvb.x, wvb.y, wvb.z, wvb.w};
            #pragma unroll
            for (int rr = 0; rr < 4; ++rr)
                #pragma unroll
                for (int jj = 0; jj < 8; ++jj)
                    acc[rr][jj] = fmaf(xf[rr], wf[jj], acc[rr][jj]);
        }
        if (tt == 19) {                            // end panel 1 [0,320)
            #pragma unroll
            for (int rr = 0; rr < 4; ++rr)
                #pragma unroll
                for (int jj = 0; jj < 8; ++jj) { cur[rr][jj] = acc[rr][jj]; acc[rr][jj] = 0.0f; }
        } else if (tt == 39) {                     // end panel 2 [320,640)
            #pragma unroll
            for (int rr = 0; rr < 4; ++rr)
                #pragma unroll
                for (int jj = 0; jj < 8; ++jj) { cur[rr][jj] = cur[rr][jj] + acc[rr][jj]; acc[rr][jj] = 0.0f; }
        }
        if (tt < 48) {                             // store prefetched tile
            const int nb = cb ^ 1;
            xs[nb][xkf + 0][xrow] = xv.x; xs[nb][xkf + 1][xrow] = xv.y;
            xs[nb][xkf + 2][xrow] = xv.z; xs[nb][xkf + 3][xrow] = xv.w;
            float* wp0 = &ws[nb][wkf][wco * 12 + wci];
            wp0[0]    = wa.x; wp0[192]  = wa.y; wp0[384]  = wa.z; wp0[576]  = wa.w;
            wp0[768]  = wb.x; wp0[960]  = wb.y; wp0[1152] = wb.z; wp0[1344] = wb.w;
        }
        __syncthreads();                           // ONE barrier per tile
    }
    {
        const float* b1p = b1 + tx * 8;
        float4 ba = *(const float4*)b1p, bb = *(const float4*)(b1p + 4);
        float bf[8] = {ba.x, ba.y, ba.z, ba.w, bb.x, bb.y, bb.z, bb.w};
        #pragma unroll
        for (int rr = 0; rr < 4; ++rr)
            #pragma unroll
            for (int jj = 0; jj < 8; ++jj)
                cur[rr][jj] = (cur[rr][jj] + acc[rr][jj]) + bf[jj];   // +P3, +b1
    }

    // ---- phase 2: LIF dynamics; layer-2 W2 via scalar loads ----
    float mem1[4][8];
    #pragma unroll
    for (int rr = 0; rr < 4; ++rr)
        #pragma unroll
        for (int jj = 0; jj < 8; ++jj) mem1[rr][jj] = 0.0f;

    const int row_l2 = t & 63;                     // layer-2: row
    const int ogu    = __builtin_amdgcn_readfirstlane(t >> 6);  // wave-uniform
    const float4* __restrict__ w2t = w2tab + (size_t)ogu * NJ;  // uniform base
    float b2r[4] = {0.f, 0.f, 0.f, 0.f};
    if (ogu < 3) {
        #pragma unroll
        for (int c = 0; c < 4; ++c) {
            int o = ogu * 4 + c;
            b2r[c] = (o < NO) ? b2[o] : 0.0f;      // same values as old b2s
        }
    }
    float m2[4]  = {0.f, 0.f, 0.f, 0.f};
    float cnt[4] = {0.f, 0.f, 0.f, 0.f};
    float* rec = out + (size_t)B * NO;

    #pragma unroll 1
    for (int st = 0; st < TSTEPS; ++st) {
        const int p = st & 1;
        #pragma unroll
        for (int rr = 0; rr < 4; ++rr) {
            unsigned bt = 0;
            float s0[8];
            #pragma unroll
            for (int jj = 0; jj < 8; ++jj) {
                float m = fmaf(mem1[rr][jj], 0.25f, cur[rr][jj]);  // *0.25 exact
                float v = m - 1.0f;
                bool  s = v > 0.0f;
                s0[jj] = s ? 1.0f : 0.0f;
                mem1[rr][jj] = s ? 0.0f : m;
                bt |= s ? (1u << jj) : 0u;
            }
            size_t base = ((size_t)st * B + (size_t)(r0 + ty * 4 + rr)) * NJ + tx * 8;
            f32x4 fa = {s0[0], s0[1], s0[2], s0[3]};
            f32x4 fb = {s0[4], s0[5], s0[6], s0[7]};
            __builtin_nontemporal_store(fa, (f32x4*)&rec[base]);
            __builtin_nontemporal_store(fb, (f32x4*)&rec[base + 4]);
            ((unsigned char*)&smaskW[p][ty * 4 + rr][0])[tx] = (unsigned char)bt;
        }
        // Non-draining barrier (r13): LDS visibility only; NT stores float.
        asm volatile("s_waitcnt lgkmcnt(0)\n\ts_barrier" ::: "memory");
        if (ogu < 3) {                             // wave-uniform branch
            unsigned mw[4];
            #pragma unroll
            for (int w = 0; w < 4; ++w) mw[w] = smaskW[p][row_l2][w];
            float mm[4] = {0.f, 0.f, 0.f, 0.f};
            #pragma unroll
            for (int w = 0; w < 4; ++w) {
                unsigned bits = mw[w];
                #pragma unroll
                for (int b = 0; b < 32; ++b) {     // strict ascending j
                    float f = (float)(bits & (1u << b));      // 0 or 2^b, exact
                    float4 wv = w2t[w * 32 + b];              // uniform -> s_load
                    mm[0] = fmaf(f, wv.x, mm[0]);
                    mm[1] = fmaf(f, wv.y, mm[1]);
                    mm[2] = fmaf(f, wv.z, mm[2]);
                    mm[3] = fmaf(f, wv.w, mm[3]);
                }
            }
            #pragma unroll
            for (int c = 0; c < 4; ++c) {
                float cur2 = mm[c] + b2r[c];            // np: chain + b2
                float nm   = fmaf(m2[c], 0.25f, cur2);  // then decay add (exact mul)
                float v2   = nm - 1.0f;
                bool  s2   = v2 > 0.0f;
                cnt[c] += s2 ? 1.0f : 0.0f;
                m2[c]  = s2 ? 0.0f : nm;
            }
        }
    }

    if (ogu < 3) {
        #pragma unroll
        for (int c = 0; c < 4; ++c) {
            int o = ogu * 4 + c;
            if (o < NO) out[(size_t)(r0 + row_l2) * NO + o] = cnt[c];
        }
    }
}

extern "C" void kernel_launch(void* const* d_in, const int* in_sizes, int n_in,
                              void* d_out, int out_size, void* d_ws, size_t ws_size,
                              hipStream_t stream)
{
    const float* x  = (const float*)d_in[0];
    const float* W1 = (const float*)d_in[1];
    const float* b1 = (const float*)d_in[2];
    const float* W2 = (const float*)d_in[3];
    const float* b2 = (const float*)d_in[4];
    float* out = (float*)d_out;
    float4* w2t = (float4*)d_ws;            // 6 KB table, untouched by out writes
    const int B = in_sizes[0] / KDIM;       // 32768
    snn_prep<<<1, 256, 0, stream>>>(W2, w2t);
    snn_fused<<<B / BROWS, 256, 0, stream>>>(x, W1, b1, w2t, b2, out, B);
}